// Round 1
// baseline (385.660 us; speedup 1.0000x reference)
//
#include <hip/hip_runtime.h>
#include <math.h>

// SE block: x[32,512,56,56] fp32
//   s[b,c]   = mean_{h,w} x[b,c,h,w]                       (pool)
//   h[b,m]   = relu(sum_c s[b,c]*w1[m,c] + b1[m])  m<32    (excite 1)
//   g[b,c]   = sigmoid(sum_m h[b,m]*w2[c,m] + b2[c])       (excite 2)
//   out      = x * g[b,c]                                   (scale)
//
// B*C = 16384 planes, each plane = 3136 contiguous floats = 784 float4.

#define NPLANE 16384
#define PLANE_F4 784   // 3136 floats / 4
#define C_DIM 512
#define MID 32

// ---------------- Kernel 1: per-plane mean (one wave per plane) -------------
__global__ __launch_bounds__(256) void se_pool(const float* __restrict__ x,
                                               float* __restrict__ s) {
    const int plane = (blockIdx.x * 256 + threadIdx.x) >> 6;  // global wave id
    const int lane  = threadIdx.x & 63;
    const float4* p = reinterpret_cast<const float4*>(x) + (size_t)plane * PLANE_F4;

    float sum = 0.f;
    // 784 = 12*64 + 16
    #pragma unroll
    for (int i = 0; i < 12; ++i) {
        float4 v = p[lane + i * 64];
        sum += (v.x + v.y) + (v.z + v.w);
    }
    if (lane < 16) {
        float4 v = p[768 + lane];
        sum += (v.x + v.y) + (v.z + v.w);
    }
    #pragma unroll
    for (int off = 32; off; off >>= 1) sum += __shfl_down(sum, off, 64);
    if (lane == 0) s[plane] = sum * (1.0f / 3136.0f);
}

// ---------------- Kernel 2: excitation (one block per batch b) --------------
__global__ __launch_bounds__(512) void se_excite(const float* __restrict__ s,
                                                 const float* __restrict__ w1,
                                                 const float* __restrict__ b1,
                                                 const float* __restrict__ w2,
                                                 const float* __restrict__ b2,
                                                 float* __restrict__ g) {
    __shared__ float s_lds[C_DIM];
    __shared__ float h_lds[MID];
    const int b = blockIdx.x;
    const int t = threadIdx.x;

    s_lds[t] = s[b * C_DIM + t];
    __syncthreads();

    // Stage A: h[m] = relu(dot(s, w1[m,:]) + b1[m]); 16 threads per m.
    const int m = t >> 4;      // 0..31
    const int j = t & 15;      // 0..15 (within a wave, aligned 16-group)
    float acc = 0.f;
    #pragma unroll
    for (int k = 0; k < 32; ++k) {
        const int c = j + (k << 4);
        acc += s_lds[c] * w1[m * C_DIM + c];
    }
    #pragma unroll
    for (int off = 8; off; off >>= 1) acc += __shfl_xor(acc, off, 64);
    if (j == 0) h_lds[m] = fmaxf(acc + b1[m], 0.f);
    __syncthreads();

    // Stage B: g[c] = sigmoid(dot(h, w2[c,:]) + b2[c]); one thread per c.
    float dot = 0.f;
    #pragma unroll
    for (int mm = 0; mm < MID; ++mm) dot += h_lds[mm] * w2[t * MID + mm];
    const float z = dot + b2[t];
    g[b * C_DIM + t] = 1.0f / (1.0f + expf(-z));
}

// ---------------- Kernel 3: broadcast scale (one block per plane) -----------
__global__ __launch_bounds__(256) void se_scale(const float* __restrict__ x,
                                                const float* __restrict__ g,
                                                float* __restrict__ out) {
    const int plane = blockIdx.x;
    const float gv  = g[plane];   // wave-uniform -> scalar broadcast
    const float4* px = reinterpret_cast<const float4*>(x)  + (size_t)plane * PLANE_F4;
    float4*       po = reinterpret_cast<float4*>(out)      + (size_t)plane * PLANE_F4;
    const int t = threadIdx.x;

    // 784 = 3*256 + 16
    #pragma unroll
    for (int i = 0; i < 3; ++i) {
        float4 v = px[t + i * 256];
        v.x *= gv; v.y *= gv; v.z *= gv; v.w *= gv;
        po[t + i * 256] = v;
    }
    if (t < 16) {
        float4 v = px[768 + t];
        v.x *= gv; v.y *= gv; v.z *= gv; v.w *= gv;
        po[768 + t] = v;
    }
}

extern "C" void kernel_launch(void* const* d_in, const int* in_sizes, int n_in,
                              void* d_out, int out_size, void* d_ws, size_t ws_size,
                              hipStream_t stream) {
    const float* x  = (const float*)d_in[0];
    const float* w1 = (const float*)d_in[1];
    const float* b1 = (const float*)d_in[2];
    const float* w2 = (const float*)d_in[3];
    const float* b2 = (const float*)d_in[4];
    float* out = (float*)d_out;

    float* s = (float*)d_ws;            // 16384 floats
    float* g = s + NPLANE;              // 16384 floats

    // 1) pool: one wave per plane, 4 waves per block -> 4096 blocks
    se_pool<<<NPLANE / 4, 256, 0, stream>>>(x, s);
    // 2) excitation: one block per batch row
    se_excite<<<32, 512, 0, stream>>>(s, w1, b1, w2, b2, g);
    // 3) scale: one block per plane
    se_scale<<<NPLANE, 256, 0, stream>>>(x, g, out);
}

// Round 3
// 381.130 us; speedup vs baseline: 1.0119x; 1.0119x over previous
//
#include <hip/hip_runtime.h>
#include <math.h>

// SE block: x[32,512,56,56] fp32
//   s[b,c] = mean_{h,w} x[b,c,h,w]
//   h[b,m] = relu(s @ w1^T + b1), m<32
//   g[b,c] = sigmoid(h @ w2^T + b2)
//   out    = x * g[b,c]
//
// B*C = 16384 planes, each plane = 3136 contiguous floats = 784 float4.
// Plane-per-wave grid-stride for pool and scale (one wave reads a contiguous
// 12.5 KB plane -> perfectly coalesced 1 KB/instr float4 loads). Output
// stores are nontemporal (nt) so the 205 MB of `out` does not evict x from
// the 256 MB Infinity Cache -> scale's re-read of x should be L3-resident.

typedef float f32x4 __attribute__((ext_vector_type(4)));  // native vector:
// __builtin_nontemporal_store accepts this (HIP's float4 class is rejected).

#define NPLANE   16384
#define PLANE_F4 784     // 3136 floats / 4
#define C_DIM    512
#define MID      32
#define NBLOCKS  2048    // 8 blocks/CU on 256 CUs
#define NWAVES   (NBLOCKS * 4)

// ---------------- Kernel 1: per-plane mean (one wave per plane) -------------
__global__ __launch_bounds__(256) void se_pool(const float* __restrict__ x,
                                               float* __restrict__ s) {
    const int wave0 = (blockIdx.x * 256 + threadIdx.x) >> 6;
    const int lane  = threadIdx.x & 63;

    for (int plane = wave0; plane < NPLANE; plane += NWAVES) {
        const f32x4* p = reinterpret_cast<const f32x4*>(x) + (size_t)plane * PLANE_F4;
        float sum = 0.f;
        // 784 = 12*64 + 16
        #pragma unroll
        for (int i = 0; i < 12; ++i) {
            f32x4 v = p[lane + (i << 6)];
            sum += (v.x + v.y) + (v.z + v.w);
        }
        if (lane < 16) {
            f32x4 v = p[768 + lane];
            sum += (v.x + v.y) + (v.z + v.w);
        }
        #pragma unroll
        for (int off = 32; off; off >>= 1) sum += __shfl_down(sum, off, 64);
        if (lane == 0) s[plane] = sum * (1.0f / 3136.0f);
    }
}

// ---------------- Kernel 2: excitation (one block per batch b) --------------
__global__ __launch_bounds__(512) void se_excite(const float* __restrict__ s,
                                                 const float* __restrict__ w1,
                                                 const float* __restrict__ b1,
                                                 const float* __restrict__ w2,
                                                 const float* __restrict__ b2,
                                                 float* __restrict__ g) {
    __shared__ float s_lds[C_DIM];
    __shared__ float h_lds[MID];
    const int b = blockIdx.x;
    const int t = threadIdx.x;

    s_lds[t] = s[b * C_DIM + t];
    __syncthreads();

    // Stage A: h[m] = relu(dot(s, w1[m,:]) + b1[m]); 16 threads per m.
    const int m = t >> 4;      // 0..31
    const int j = t & 15;      // 0..15
    float acc = 0.f;
    #pragma unroll
    for (int k = 0; k < 32; ++k) {
        const int c = j + (k << 4);
        acc += s_lds[c] * w1[m * C_DIM + c];
    }
    #pragma unroll
    for (int off = 8; off; off >>= 1) acc += __shfl_xor(acc, off, 64);
    if (j == 0) h_lds[m] = fmaxf(acc + b1[m], 0.f);
    __syncthreads();

    // Stage B: g[c] = sigmoid(dot(h, w2[c,:]) + b2[c]); one thread per c.
    float dot = 0.f;
    #pragma unroll
    for (int mm = 0; mm < MID; ++mm) dot += h_lds[mm] * w2[t * MID + mm];
    const float z = dot + b2[t];
    g[b * C_DIM + t] = 1.0f / (1.0f + expf(-z));
}

// ---------------- Kernel 3: scale (one wave per plane, nt stores) -----------
__global__ __launch_bounds__(256) void se_scale(const float* __restrict__ x,
                                                const float* __restrict__ g,
                                                float* __restrict__ out) {
    const int wave0 = (blockIdx.x * 256 + threadIdx.x) >> 6;
    const int lane  = threadIdx.x & 63;

    for (int plane = wave0; plane < NPLANE; plane += NWAVES) {
        const float gv = g[plane];
        const f32x4* px = reinterpret_cast<const f32x4*>(x)  + (size_t)plane * PLANE_F4;
        f32x4*       po = reinterpret_cast<f32x4*>(out)      + (size_t)plane * PLANE_F4;
        #pragma unroll
        for (int i = 0; i < 12; ++i) {
            f32x4 v = px[lane + (i << 6)];
            v *= gv;
            __builtin_nontemporal_store(v, &po[lane + (i << 6)]);
        }
        if (lane < 16) {
            f32x4 v = px[768 + lane];
            v *= gv;
            __builtin_nontemporal_store(v, &po[768 + lane]);
        }
    }
}

extern "C" void kernel_launch(void* const* d_in, const int* in_sizes, int n_in,
                              void* d_out, int out_size, void* d_ws, size_t ws_size,
                              hipStream_t stream) {
    const float* x  = (const float*)d_in[0];
    const float* w1 = (const float*)d_in[1];
    const float* b1 = (const float*)d_in[2];
    const float* w2 = (const float*)d_in[3];
    const float* b2 = (const float*)d_in[4];
    float* out = (float*)d_out;

    float* s = (float*)d_ws;            // 16384 floats
    float* g = s + NPLANE;              // 16384 floats

    se_pool <<<NBLOCKS, 256, 0, stream>>>(x, s);
    se_excite<<<32, 512, 0, stream>>>(s, w1, b1, w2, b2, g);
    se_scale<<<NBLOCKS, 256, 0, stream>>>(x, g, out);
}